// Round 1
// baseline (565.725 us; speedup 1.0000x reference)
//
#include <hip/hip_runtime.h>
#include <hip/hip_bf16.h>
#include <stdint.h>

// out[b,o] = sum_{k,i} hyp[b,k] * h[b,i] * W2[k, i*256+o] + sum_i h[b,i]*b2[i*256+o] + bias[o]
// == GEMM: A[4096 x 131328] * B[131328 x 256], where
//   flat K = k*256+i (W2 part, 131072) then 256 extra rows for b2 (scale 1)
//   A generated on the fly: A[b, t*64+c] = scale(b, t>>2) * h[b, (t&3)*64+c]
//   B = W2 flattened row-major [131072,256] (identity reshape), pre-packed to bf16
//     in per-tile [col:256][k:64] transposed layout with XOR swizzle baked in.
//
// ws layout: [0, 8MB) hyp fp32 [4096][512]; [8MB, +67.2MB) packed B bf16 (2052 tiles)
// needs ws_size >= 75,628,544 bytes.

typedef __bf16 bf16x8 __attribute__((ext_vector_type(8)));
typedef float  f32x4  __attribute__((ext_vector_type(8/2)));

#define KTILES      2052     // 2048 W2 tiles + 4 b2 tiles, 64 flat-K each
#define TILE_BYTES  32768    // 256 cols * 64 k * 2 B

// ---------------- out = bias ----------------
__global__ void k_init_out(const float* __restrict__ bias, float* __restrict__ out) {
    int idx = blockIdx.x * 256 + threadIdx.x;   // grid 4096 x 256 == 1,048,576
    out[idx] = bias[idx & 255];
}

// ---------------- hyp = relu(z @ W1 + b1), fp32 ----------------
__global__ void k_hyp(const float* __restrict__ z, const float* __restrict__ W1,
                      const float* __restrict__ b1, float* __restrict__ hyp) {
    __shared__ float zs[128];
    int b = blockIdx.x;           // 4096 blocks
    int j = threadIdx.x;          // 256 threads, cols j and j+256
    if (j < 128) zs[j] = z[b * 128 + j];
    __syncthreads();
    float a0 = b1[j], a1 = b1[j + 256];
#pragma unroll 8
    for (int c = 0; c < 128; ++c) {
        float zc = zs[c];
        a0 += zc * W1[c * 512 + j];        // coalesced, W1 (256KB) L2-resident
        a1 += zc * W1[c * 512 + j + 256];
    }
    hyp[b * 512 + j]       = a0 > 0.f ? a0 : 0.f;
    hyp[b * 512 + j + 256] = a1 > 0.f ? a1 : 0.f;
}

// ---------------- pack W2 (+b2) -> bf16 transposed+swizzled tiles ----------------
// tile t covers flat-K rows [t*64, t*64+64). Within tile, element (kk, o) at byte
//   (o*128 + kk*2) ^ ((o&7)<<4)
__global__ void k_pack(const float* __restrict__ W2, const float* __restrict__ b2,
                       uint16_t* __restrict__ Bp) {
    int t = blockIdx.x;        // 0..2051
    int o = threadIdx.x;       // 0..255 (output column)
    long row0 = (long)t * 64;
    const float* src = (t < 2048) ? (W2 + row0 * 256) : (b2 + (row0 - 131072) * 256);
    char* dst = (char*)Bp + (size_t)t * TILE_BYTES;
    int swz = (o & 7) << 4;
#pragma unroll
    for (int k8 = 0; k8 < 8; ++k8) {
        bf16x8 v;
#pragma unroll
        for (int q = 0; q < 8; ++q)
            v[q] = (__bf16)src[(k8 * 8 + q) * 256 + o];   // lanes: consecutive o -> coalesced
        *(bf16x8*)(dst + ((o * 128 + k8 * 16) ^ swz)) = v;
    }
}

// ---------------- main GEMM: BM=128, BN=128, BK=64, 4 waves, split-K x17 ----------------
__global__ __launch_bounds__(256) void k_gemm(
        const float* __restrict__ h, const float* __restrict__ hyp,
        const uint16_t* __restrict__ Bp, float* __restrict__ out) {
    __shared__ char smem[32768];   // [0,16K): A tile 128x64 bf16 swz; [16K,32K): B tile 128x64

    const int tid  = threadIdx.x;
    const int lane = tid & 63;
    const int wid  = tid >> 6;           // 4 waves
    const int wm   = wid >> 1, wn = wid & 1;
    const int l15  = lane & 15, lg = lane >> 4;

    // slab-major block order: 64 blocks per K-slab share the same 4MB Bp slab
    int bid = blockIdx.x;                // 17*64 = 1088 blocks
    int s   = bid >> 6;                  // K-slab 0..16
    int mn  = bid & 63;
    int mt  = mn >> 1, nt = mn & 1;
    int t0  = s * 128;
    int ntile = (s == 16) ? 4 : 128;     // slab 16 = the b2 mini-slab
    const int row_base = mt * 128;

    const int cc = tid & 7;              // A-staging: 16B chunk within row
    const int r0 = tid >> 3;             // A-staging: base row 0..31

    f32x4 acc[4][4];
#pragma unroll
    for (int i = 0; i < 4; ++i)
#pragma unroll
        for (int j = 0; j < 4; ++j)
#pragma unroll
            for (int q = 0; q < 4; ++q) acc[i][j][q] = 0.0f;

    for (int it = 0; it < ntile; ++it) {
        int t  = t0 + it;
        int k  = t >> 2;                 // hypernet k (512 => b2 slab, scale 1)
        int i0 = (t & 3) << 6;
        __syncthreads();                 // previous compute done before LDS overwrite

        // ---- B half-tile: linear 16KB global->LDS (pre-swizzled source) ----
        {
            const char* gsrc = (const char*)Bp + (size_t)t * TILE_BYTES + nt * 16384;
#pragma unroll
            for (int q = 0; q < 4; ++q) {
                int off = wid * 4096 + q * 1024;
                __builtin_amdgcn_global_load_lds(
                    (const __attribute__((address_space(1))) void*)(gsrc + off + lane * 16),
                    (__attribute__((address_space(3))) void*)(smem + 16384 + off),
                    16, 0, 0);
            }
        }
        // ---- A tile: a[r][c] = scale(row,k) * h[row, i0+c], bf16, XOR-swizzled ----
        {
            bool use_hyp = (k < 512);    // wave-uniform
#pragma unroll
            for (int j = 0; j < 4; ++j) {
                int r    = r0 + j * 32;
                int grow = row_base + r;
                float sc = use_hyp ? hyp[grow * 512 + k] : 1.0f;
                const f32x4* hp = (const f32x4*)(h + grow * 256 + i0 + cc * 8);
                f32x4 h0 = hp[0], h1 = hp[1];
                bf16x8 v;
                v[0] = (__bf16)(sc * h0[0]); v[1] = (__bf16)(sc * h0[1]);
                v[2] = (__bf16)(sc * h0[2]); v[3] = (__bf16)(sc * h0[3]);
                v[4] = (__bf16)(sc * h1[0]); v[5] = (__bf16)(sc * h1[1]);
                v[6] = (__bf16)(sc * h1[2]); v[7] = (__bf16)(sc * h1[3]);
                int off = (r * 128 + cc * 16) ^ ((r & 7) << 4);
                *(bf16x8*)(smem + off) = v;
            }
        }
        __syncthreads();                 // compiler drains vmcnt/lgkmcnt here

        // ---- compute: 2 k-subtiles of 32, 32 MFMAs/wave ----
#pragma unroll
        for (int ks = 0; ks < 2; ++ks) {
            bf16x8 af[4], bfr[4];
#pragma unroll
            for (int mf = 0; mf < 4; ++mf) {
                int row = wm * 64 + mf * 16 + l15;
                int off = (row * 128 + ks * 64 + lg * 16) ^ ((row & 7) << 4);
                af[mf] = *(const bf16x8*)(smem + off);
            }
#pragma unroll
            for (int nf = 0; nf < 4; ++nf) {
                int col = wn * 64 + nf * 16 + l15;
                int off = (col * 128 + ks * 64 + lg * 16) ^ ((col & 7) << 4);
                bfr[nf] = *(const bf16x8*)(smem + 16384 + off);
            }
#pragma unroll
            for (int mf = 0; mf < 4; ++mf)
#pragma unroll
                for (int nf = 0; nf < 4; ++nf)
                    acc[mf][nf] = __builtin_amdgcn_mfma_f32_16x16x32_bf16(
                        af[mf], bfr[nf], acc[mf][nf], 0, 0, 0);
        }
    }

    // ---- epilogue: atomic split-K accumulate (out pre-initialized with bias) ----
    int crow0 = row_base + wm * 64;
    int ccol0 = nt * 128 + wn * 64;
#pragma unroll
    for (int mf = 0; mf < 4; ++mf)
#pragma unroll
        for (int nf = 0; nf < 4; ++nf) {
            int col = ccol0 + nf * 16 + l15;
#pragma unroll
            for (int q = 0; q < 4; ++q) {
                int row = crow0 + mf * 16 + lg * 4 + q;   // C/D: col=lane&15, row=(lane>>4)*4+q
                atomicAdd(&out[row * 256 + col], acc[mf][nf][q]);
            }
        }
}

extern "C" void kernel_launch(void* const* d_in, const int* in_sizes, int n_in,
                              void* d_out, int out_size, void* d_ws, size_t ws_size,
                              hipStream_t stream) {
    const float* h    = (const float*)d_in[0];  // [4096,256]
    const float* z    = (const float*)d_in[1];  // [4096,128]
    const float* W1   = (const float*)d_in[2];  // [128,512]
    const float* b1   = (const float*)d_in[3];  // [512]
    const float* W2   = (const float*)d_in[4];  // [512,65536]
    const float* b2   = (const float*)d_in[5];  // [65536]
    const float* bias = (const float*)d_in[6];  // [1,256]
    float* out = (float*)d_out;                 // [4096,256] fp32

    float*    hyp = (float*)d_ws;                                   // 8 MB
    uint16_t* Bp  = (uint16_t*)((char*)d_ws + 8u * 1024u * 1024u);  // 67.2 MB

    k_pack    <<<KTILES, 256, 0, stream>>>(W2, b2, Bp);
    k_hyp     <<<4096,   256, 0, stream>>>(z, W1, b1, hyp);
    k_init_out<<<4096,   256, 0, stream>>>(bias, out);
    k_gemm    <<<17 * 64, 256, 0, stream>>>(h, hyp, Bp, out);
}